// Round 14
// baseline (44420.743 us; speedup 1.0000x reference)
//
#include <hip/hip_runtime.h>
#include <hip/hip_bf16.h>
#include <math.h>

// Problem constants
#define T_STEPS 8192
#define HDIM    1024
#define GW      128     // workgroups per scan kernel (1 per CU, all co-resident)
#define NSLOT   512     // one slot per wave: 2 h-values + tag
#define SLOT_PITCH 256  // bytes between slots: spread across MALL channels
#define NREP    8       // producer-side replicas; consumer WG g polls replica g&7
#define REP_STRIDE ((size_t)2 * NSLOT * SLOT_PITCH)   // 256 KB per replica

// Workspace layout (bytes)
#define OFF_REV   ((size_t)0)                         // 8192*64*4   = 2 MB
#define OFF_X1    ((size_t)2097152)                   // 8192*512*4  = 16 MB (reused as slots after gemm2)
#define OFF_B     ((size_t)18874368)                  // x2: 8192*1024*4 = 32 MB (read by fused gru scan)
#define OFF_C     ((size_t)52428800)                  // y1: 8192*512*4 = 16 MB (written by fused lstm scan)
#define WS_NEEDED ((size_t)153092096)

typedef float f4 __attribute__((ext_vector_type(4)));

__device__ inline float sigm(float x)   { return 1.0f / (1.0f + __expf(-x)); }
__device__ inline float tanh_f(float x) { float e = __expf(2.0f * x); return 1.0f - 2.0f / (e + 1.0f); }

// slot k of buffer b, replica rep
__device__ inline f4* slot_ptr(char* base, int rep, int b, int k) {
    return (f4*)(base + (size_t)rep * REP_STRIDE + ((size_t)b * NSLOT + k) * SLOT_PITCH);
}

// Device-coherent (L1+L2-bypassing) 16B store: tag travels with data in one
// transaction. MALL is the only working coherence point (R4/R5: remote
// stores never refresh another L2's stale line; sc0-only polling unsound).
__device__ inline void store_cohr(f4* p, f4 v) {
    asm volatile("global_store_dwordx4 %0, %1, off sc0 sc1"
                 :: "v"(p), "v"(v) : "memory");
}

// Split poll: issue the paired probe (non-blocking) -> caller runs
// PURE-REGISTER work while the loads are in flight -> wait+check.
// CAUTION: between issue and wait, the caller must not execute
// compiler-generated memory loads (compiler vmcnt bookkeeping does not
// see the asm probes -> undercounted waits -> garbage reads).
__device__ inline void issue_pair(const f4* p, f4& a, f4& b) {
    asm volatile("global_load_dwordx4 %0, %2, off sc0 sc1\n\t"
                 "global_load_dwordx4 %1, %2, off offset:256 sc0 sc1"
                 : "=&v"(a), "=&v"(b) : "v"(p) : "memory");
}
__device__ inline void wait_pair(f4& a, f4& b) {
    asm volatile("s_waitcnt vmcnt(0)" : "+v"(a), "+v"(b) :: "memory");
}

// Classic throttled poll loop (R7/R12): reissue + vmcnt(0) + sleep.
__device__ inline void poll_pair(const f4* p, unsigned want, f4& a, f4& b) {
    for (;;) {
        f4 va, vb;
        asm volatile("global_load_dwordx4 %0, %2, off sc0 sc1\n\t"
                     "global_load_dwordx4 %1, %2, off offset:256 sc0 sc1\n\t"
                     "s_waitcnt vmcnt(0)"
                     : "=&v"(va), "=&v"(vb) : "v"(p) : "memory");
        if (__float_as_uint(va.w) == want && __float_as_uint(vb.w) == want) {
            a = va; b = vb; return;
        }
        __builtin_amdgcn_s_sleep(1);
    }
}

// ---------------------------------------------------------------------------
// build rev: rev[t][0:32]=weather[T-1-t], rev[t][32:64]=infect[T-1-t]
// ---------------------------------------------------------------------------
__global__ void build_rev(const float* __restrict__ wea, const float* __restrict__ inf,
                          float* __restrict__ rev) {
    int idx = blockIdx.x * blockDim.x + threadIdx.x;   // over T*64
    if (idx >= T_STEPS * 64) return;
    int t = idx >> 6, c = idx & 63;
    int ts = T_STEPS - 1 - t;
    rev[idx] = (c < 32) ? wea[ts * 32 + c] : inf[ts * 32 + (c - 32)];
}

// ---------------------------------------------------------------------------
// seed ALL replicas: buffer 0 with h_init (tag 0), buffer 1 with poison tag
// ---------------------------------------------------------------------------
__global__ void seed_slots(const float* __restrict__ h0, char* __restrict__ sb) {
    int i = blockIdx.x * blockDim.x + threadIdx.x;   // over NREP*2*NSLOT = 8192
    int rep = i >> 10;            // replica index 0..7
    int j   = i & 1023;           // buf*NSLOT + k
    if (rep < NREP) {
        if (j < NSLOT) {
            f4 v;
            v.x = h0[2 * j]; v.y = h0[2 * j + 1]; v.z = 0.0f;
            v.w = __uint_as_float(0u);
            store_cohr(slot_ptr(sb, rep, 0, j), v);
        } else {
            f4 v;
            v.x = 0.f; v.y = 0.f; v.z = 0.f;
            v.w = __uint_as_float(0xFFFFFFFFu);      // poison tag
            store_cohr(slot_ptr(sb, rep, 1, j - NSLOT), v);
        }
    }
}

// ---------------------------------------------------------------------------
// Tiled f32 GEMM: C[M,N] = act(A[M,K] @ W[N,K]^T + bias[N]); BM=BN=64, BK=32
// (encoder layers only; xp and decoder GEMMs are fused into the scans)
// ---------------------------------------------------------------------------
__global__ __launch_bounds__(256) void gemm_bias_act(
    const float* __restrict__ A, const float* __restrict__ W,
    const float* __restrict__ bias, float* __restrict__ C,
    int M, int N, int K, int relu)
{
    __shared__ float As[32][68];
    __shared__ float Ws[32][68];
    const int tid = threadIdx.x;
    const int tx = tid & 15, ty = tid >> 4;
    const int bm = blockIdx.y, bn = blockIdx.x;
    const float* Ab = A + (size_t)bm * 64 * K;
    const float* Wb = W + (size_t)bn * 64 * K;
    float acc[4][4] = {};

    for (int k0 = 0; k0 < K; k0 += 32) {
#pragma unroll
        for (int q = 0; q < 2; ++q) {
            int idx = tid * 2 + q;           // 0..511
            int row = idx >> 3;              // 0..63
            int kc  = (idx & 7) << 2;        // 0..28
            float4 av = *(const float4*)(Ab + (size_t)row * K + k0 + kc);
            As[kc + 0][row] = av.x; As[kc + 1][row] = av.y;
            As[kc + 2][row] = av.z; As[kc + 3][row] = av.w;
            float4 wv = *(const float4*)(Wb + (size_t)row * K + k0 + kc);
            Ws[kc + 0][row] = wv.x; Ws[kc + 1][row] = wv.y;
            Ws[kc + 2][row] = wv.z; Ws[kc + 3][row] = wv.w;
        }
        __syncthreads();
#pragma unroll
        for (int k = 0; k < 32; ++k) {
            float4 a = *(const float4*)&As[k][ty << 2];
            float4 b = *(const float4*)&Ws[k][tx << 2];
            acc[0][0] += a.x*b.x; acc[0][1] += a.x*b.y; acc[0][2] += a.x*b.z; acc[0][3] += a.x*b.w;
            acc[1][0] += a.y*b.x; acc[1][1] += a.y*b.y; acc[1][2] += a.y*b.z; acc[1][3] += a.y*b.w;
            acc[2][0] += a.z*b.x; acc[2][1] += a.z*b.y; acc[2][2] += a.z*b.z; acc[2][3] += a.z*b.w;
            acc[3][0] += a.w*b.x; acc[3][1] += a.w*b.y; acc[3][2] += a.w*b.z; acc[3][3] += a.w*b.w;
        }
        __syncthreads();
    }

    int m0 = bm * 64 + (ty << 2), n0 = bn * 64 + (tx << 2);
    float4 bv = *(const float4*)(bias + n0);
#pragma unroll
    for (int r = 0; r < 4; ++r) {
        float4 o;
        o.x = acc[r][0] + bv.x; o.y = acc[r][1] + bv.y;
        o.z = acc[r][2] + bv.z; o.w = acc[r][3] + bv.w;
        if (relu) {
            o.x = fmaxf(o.x, 0.f); o.y = fmaxf(o.y, 0.f);
            o.z = fmaxf(o.z, 0.f); o.w = fmaxf(o.w, 0.f);
        }
        *(float4*)(C + (size_t)(m0 + r) * N + n0) = o;
    }
}

// ---------------------------------------------------------------------------
// GRU scan with FUSED input projection, probe-overlapped.
// Iteration t: issue probes -> compute xp[t] from x2 regs PREFETCHED last
// iteration (pure VALU+shuffle, overlaps probe flight) -> wait/check ->
// stage/barrier -> prefetch x2[t+1] regs (completes under hh compute; touch
// forces the waitcnt BEFORE publish so no compiler loads cross the probes)
// -> hh compute -> gate -> replicated publish.
// ---------------------------------------------------------------------------
__global__ __launch_bounds__(256, 1) void gru_scan(
    const float* __restrict__ whh,   // 3072x1024
    const float* __restrict__ bhh,   // 3072
    const float* __restrict__ wih,   // 3072x1024
    const float* __restrict__ bih,   // 3072
    const float* __restrict__ x2,    // 8192x1024 (encoder output)
    char* __restrict__ sb)           // slot base: NREP x 2 x NSLOT x 256B
{
    __shared__ float h_sh[2][HDIM];
    const int g = blockIdx.x, tid = threadIdx.x;
    const int w = tid >> 6, l = tid & 63;
    const int wv = g * 4 + w;
    const int rep = g & (NREP - 1);
    const int iA = 2 * wv, iB = iA + 1;
    const int rows[6] = { iA, HDIM + iA, 2*HDIM + iA, iB, HDIM + iB, 2*HDIM + iB };

    // weights -> VGPRs: lane l holds w[row][256j + 4l .. +3]
    f4 Wf[6][4], Wi[6][4];
#pragma unroll
    for (int r = 0; r < 6; ++r) {
        const float* wr = whh + (size_t)rows[r] * HDIM + 4 * l;
        const float* wr2 = wih + (size_t)rows[r] * HDIM + 4 * l;
#pragma unroll
        for (int j = 0; j < 4; ++j) {
            Wf[r][j] = *(const f4*)(wr + 256 * j);
            Wi[r][j] = *(const f4*)(wr2 + 256 * j);
        }
    }
#pragma unroll
    for (int r = 0; r < 6; ++r)
#pragma unroll
        for (int j = 0; j < 4; ++j) {
            asm volatile("" : "+v"(Wf[r][j]));   // pin: opaque def, cannot remat
            asm volatile("" : "+v"(Wi[r][j]));
        }

    // per-output constants on lanes 0 (output iA) and 1 (output iB)
    float b0 = 0.f, b1 = 0.f, b2 = 0.f;
    float bi0 = 0.f, bi1 = 0.f, bi2 = 0.f;
    int xrow = (l == 0) ? iA : iB;
    if (l < 2) {
        b0  = bhh[xrow]; b1  = bhh[HDIM + xrow]; b2  = bhh[2*HDIM + xrow];
        bi0 = bih[xrow]; bi1 = bih[HDIM + xrow]; bi2 = bih[2*HDIM + xrow];
    }

    // prologue: prefetch x2[0] into registers and force completion
    f4 x4p[4];
    {
        const float* xr = x2 + 4 * l;
#pragma unroll
        for (int j = 0; j < 4; ++j) x4p[j] = *(const f4*)(xr + 256 * j);
#pragma unroll
        for (int j = 0; j < 4; ++j) asm volatile("" : "+v"(x4p[j]));
    }

    for (int t = 0; t < T_STEPS; ++t) {
        const int buf = t & 1;
        const f4* pp = slot_ptr(sb, rep, buf, 2 * tid);
        f4 sa, sb2;
        issue_pair(pp, sa, sb2);                    // probes in flight

        // xp for step t from x4p (pure register work; overlaps probe RT)
        float xv0 = 0.f, xv1 = 0.f, xv2 = 0.f;
        {
            float xred[6];
#pragma unroll
            for (int r = 0; r < 6; ++r) {
                f4 p = Wi[r][0]*x4p[0] + Wi[r][1]*x4p[1] + Wi[r][2]*x4p[2] + Wi[r][3]*x4p[3];
                float v = p.x + p.y + p.z + p.w;
#pragma unroll
                for (int off = 32; off > 0; off >>= 1) v += __shfl_xor(v, off, 64);
                xred[r] = v;
            }
            if (l < 2) {
                xv0 = ((l == 0) ? xred[0] : xred[3]) + bi0;
                xv1 = ((l == 0) ? xred[1] : xred[4]) + bi1;
                xv2 = ((l == 0) ? xred[2] : xred[5]) + bi2;
            }
        }

        wait_pair(sa, sb2);
        if (!(__float_as_uint(sa.w) == (unsigned)t && __float_as_uint(sb2.w) == (unsigned)t)) {
            __builtin_amdgcn_s_sleep(1);
            poll_pair(pp, (unsigned)t, sa, sb2);
        }
        h_sh[buf][4*tid + 0] = sa.x;  h_sh[buf][4*tid + 1] = sa.y;
        h_sh[buf][4*tid + 2] = sb2.x; h_sh[buf][4*tid + 3] = sb2.y;
        __syncthreads();

        f4 h4[4];
#pragma unroll
        for (int j = 0; j < 4; ++j) h4[j] = *(const f4*)&h_sh[buf][256*j + 4*l];

        // prefetch x2[t+1] (completes under the hh compute below)
        {
            int tn = (t + 1 < T_STEPS) ? (t + 1) : t;
            const float* xr = x2 + (size_t)tn * HDIM + 4 * l;
#pragma unroll
            for (int j = 0; j < 4; ++j) x4p[j] = *(const f4*)(xr + 256 * j);
        }

        float red[6];
#pragma unroll
        for (int r = 0; r < 6; ++r) {
            f4 p = Wf[r][0]*h4[0] + Wf[r][1]*h4[1] + Wf[r][2]*h4[2] + Wf[r][3]*h4[3];
            float v = p.x + p.y + p.z + p.w;
#pragma unroll
            for (int off = 32; off > 0; off >>= 1) v += __shfl_xor(v, off, 64);
            red[r] = v;
        }

        // force x4p completion NOW (compiler vmcnt count accurate here: the
        // asm probes were fully drained at wait_pair/poll_pair)
#pragma unroll
        for (int j = 0; j < 4; ++j) asm volatile("" : "+v"(x4p[j]));

        // gate math: lane0 -> output iA, lane1 -> output iB
        float hn = 0.f;
        if (l < 2) {
            float rd0 = (l == 0) ? red[0] : red[3];
            float rd1 = (l == 0) ? red[1] : red[4];
            float rd2 = (l == 0) ? red[2] : red[5];
            float hh_r = rd0 + b0, hh_z = rd1 + b1, hh_n = rd2 + b2;
            float r_ = sigm(xv0 + hh_r);
            float z_ = sigm(xv1 + hh_z);
            float n_ = tanh_f(xv2 + r_ * hh_n);
            float hp = h_sh[buf][xrow];
            hn = (1.0f - z_) * n_ + z_ * hp;
        }
        float hAv = __shfl(hn, 0, 64);
        float hBv = __shfl(hn, 1, 64);
        if (l < NREP) {
            unsigned pub = (unsigned)(t + 1);
            f4 s; s.x = hAv; s.y = hBv; s.z = 0.0f; s.w = __uint_as_float(pub);
            store_cohr(slot_ptr(sb, l, (int)(pub & 1), wv), s);
        }
    }
}

// ---------------------------------------------------------------------------
// LSTM-like decoder scan with FUSED first decoder layer, probe-overlapped.
// Iteration s: issue probes -> compute y1[s-2] from the PREVIOUS h4 (pure
// register work + one tiny store, overlaps probe flight) -> wait/check ->
// stage/barrier -> hh compute -> gate -> publish. Epilogue emits y1[T-1].
// ---------------------------------------------------------------------------
__global__ __launch_bounds__(256, 1) void lstm_scan(
    const float* __restrict__ wih,   // 4096x1024
    const float* __restrict__ bih,   // 4096
    const float* __restrict__ bhh,   // 4096
    const float* __restrict__ w1,    // 512x1024 (dec_w1)
    const float* __restrict__ b1,    // 512      (dec_b1)
    char* __restrict__ sb,           // slot base
    float* __restrict__ y1)          // 8192x512 output
{
    __shared__ float h_sh[2][HDIM];
    const int g = blockIdx.x, tid = threadIdx.x;
    const int w = tid >> 6, l = tid & 63;
    const int wv = g * 4 + w;
    const int rep = g & (NREP - 1);
    const int iA = 2 * wv, iB = iA + 1;
    const int rows[6] = { iA, 2*HDIM + iA, 3*HDIM + iA, iB, 2*HDIM + iB, 3*HDIM + iB };

    f4 Wf[6][4];
#pragma unroll
    for (int r = 0; r < 6; ++r) {
        const float* wr = wih + (size_t)rows[r] * HDIM + 4 * l;
#pragma unroll
        for (int j = 0; j < 4; ++j) Wf[r][j] = *(const f4*)(wr + 256 * j);
    }
    // this wave's dec_w1 row (row wv), lane l holds w1[wv][256j + 4l .. +3]
    f4 Wd[4];
    {
        const float* wr = w1 + (size_t)wv * HDIM + 4 * l;
#pragma unroll
        for (int j = 0; j < 4; ++j) Wd[j] = *(const f4*)(wr + 256 * j);
    }
#pragma unroll
    for (int r = 0; r < 6; ++r)
#pragma unroll
        for (int j = 0; j < 4; ++j)
            asm volatile("" : "+v"(Wf[r][j]));
#pragma unroll
    for (int j = 0; j < 4; ++j)
        asm volatile("" : "+v"(Wd[j]));

    const float db = b1[wv];

    float b0 = 0.f, b1_ = 0.f, b2 = 0.f;
    int xrow = (l == 0) ? iA : iB;
    if (l < 2) {
        b0  = bih[xrow]          + bhh[xrow];
        b1_ = bih[2*HDIM + xrow] + bhh[2*HDIM + xrow];
        b2  = bih[3*HDIM + xrow] + bhh[3*HDIM + xrow];
    }

    f4 hp4[4];   // h4 of the previous iteration (h_{s-2})

    for (int s = 1; s <= T_STEPS; ++s) {     // s=T_STEPS: drain-only
        const unsigned want = (unsigned)(8191 + s);
        const unsigned pub  = (unsigned)(8192 + s);
        const int buf = (int)(want & 1);
        const f4* pp = slot_ptr(sb, rep, buf, 2 * tid);
        f4 sa, sb2;
        issue_pair(pp, sa, sb2);                    // probes in flight

        // fused decoder layer 1 for h_{s-2} (overlaps probe flight)
        if (s > 1) {
            f4 p = Wd[0]*hp4[0] + Wd[1]*hp4[1] + Wd[2]*hp4[2] + Wd[3]*hp4[3];
            float v = p.x + p.y + p.z + p.w;
#pragma unroll
            for (int off = 32; off > 0; off >>= 1) v += __shfl_xor(v, off, 64);
            if (l == 0)
                y1[(size_t)(s - 2) * 512 + wv] = fmaxf(v + db, 0.f);
        }

        wait_pair(sa, sb2);
        if (!(__float_as_uint(sa.w) == want && __float_as_uint(sb2.w) == want)) {
            __builtin_amdgcn_s_sleep(1);
            poll_pair(pp, want, sa, sb2);
        }
        h_sh[buf][4*tid + 0] = sa.x;  h_sh[buf][4*tid + 1] = sa.y;
        h_sh[buf][4*tid + 2] = sb2.x; h_sh[buf][4*tid + 3] = sb2.y;
        __syncthreads();

        f4 h4[4];
#pragma unroll
        for (int j = 0; j < 4; ++j) h4[j] = *(const f4*)&h_sh[buf][256*j + 4*l];

        if (s < T_STEPS) {
            float red[6];
#pragma unroll
            for (int r = 0; r < 6; ++r) {
                f4 p = Wf[r][0]*h4[0] + Wf[r][1]*h4[1] + Wf[r][2]*h4[2] + Wf[r][3]*h4[3];
                float v = p.x + p.y + p.z + p.w;
#pragma unroll
                for (int off = 32; off > 0; off >>= 1) v += __shfl_xor(v, off, 64);
                red[r] = v;
            }

            float hn = 0.f;
            if (l < 2) {
                float rd0 = (l == 0) ? red[0] : red[3];
                float rd1 = (l == 0) ? red[1] : red[4];
                float rd2 = (l == 0) ? red[2] : red[5];
                float i_ = sigm(rd0 + b0);
                float g_ = tanh_f(rd1 + b1_);
                float o_ = sigm(rd2 + b2);
                hn = o_ * tanh_f(i_ * g_);
            }
            float hAv = __shfl(hn, 0, 64);
            float hBv = __shfl(hn, 1, 64);
            if (l < NREP) {
                f4 sv; sv.x = hAv; sv.y = hBv; sv.z = 0.0f; sv.w = __uint_as_float(pub);
                store_cohr(slot_ptr(sb, l, (int)(pub & 1), wv), sv);
            }
        }
#pragma unroll
        for (int j = 0; j < 4; ++j) hp4[j] = h4[j];
    }

    // epilogue: y1[T-1] from the final staged h (hp4 = h_{T-1})
    {
        f4 p = Wd[0]*hp4[0] + Wd[1]*hp4[1] + Wd[2]*hp4[2] + Wd[3]*hp4[3];
        float v = p.x + p.y + p.z + p.w;
#pragma unroll
        for (int off = 32; off > 0; off >>= 1) v += __shfl_xor(v, off, 64);
        if (l == 0)
            y1[(size_t)(T_STEPS - 1) * 512 + wv] = fmaxf(v + db, 0.f);
    }
}

// ---------------------------------------------------------------------------
// Final tiny GEMM: out[t][0:8] = y1[t] @ dec_w2^T + dec_b2, one wave per t
// ---------------------------------------------------------------------------
__global__ __launch_bounds__(256) void dec2_kernel(
    const float* __restrict__ y1,    // 8192x512
    const float* __restrict__ w2,    // 8x512
    const float* __restrict__ b2,    // 8
    float* __restrict__ out)         // 8192x8
{
    const int w = threadIdx.x >> 6, l = threadIdx.x & 63;
    const int t = blockIdx.x * 4 + w;
    const float* yr = y1 + (size_t)t * 512;
    float yv[8];
#pragma unroll
    for (int j = 0; j < 8; ++j) yv[j] = yr[l + 64 * j];
    float o[8];
#pragma unroll
    for (int n = 0; n < 8; ++n) {
        const float* wr = w2 + n * 512;
        float s = 0.f;
#pragma unroll
        for (int j = 0; j < 8; ++j) s += yv[j] * wr[l + 64 * j];
#pragma unroll
        for (int off = 32; off > 0; off >>= 1) s += __shfl_xor(s, off, 64);
        o[n] = s;
    }
    if (l == 0) {
#pragma unroll
        for (int n = 0; n < 8; ++n) out[(size_t)t * 8 + n] = o[n] + b2[n];
    }
}

// ---------------------------------------------------------------------------
extern "C" void kernel_launch(void* const* d_in, const int* in_sizes, int n_in,
                              void* d_out, int out_size, void* d_ws, size_t ws_size,
                              hipStream_t stream)
{
    const float* wea      = (const float*)d_in[0];
    const float* inf      = (const float*)d_in[1];
    const float* h_init   = (const float*)d_in[3];
    const float* enc_w1   = (const float*)d_in[4];
    const float* enc_b1   = (const float*)d_in[5];
    const float* enc_w2   = (const float*)d_in[6];
    const float* enc_b2   = (const float*)d_in[7];
    const float* gru_wih  = (const float*)d_in[8];
    const float* gru_whh  = (const float*)d_in[9];
    const float* gru_bih  = (const float*)d_in[10];
    const float* gru_bhh  = (const float*)d_in[11];
    const float* lstm_wih = (const float*)d_in[12];
    const float* lstm_bih = (const float*)d_in[13];
    const float* lstm_bhh = (const float*)d_in[14];
    const float* dec_w1   = (const float*)d_in[15];
    const float* dec_b1   = (const float*)d_in[16];
    const float* dec_w2   = (const float*)d_in[17];
    const float* dec_b2   = (const float*)d_in[18];

    if (ws_size < WS_NEEDED) return;

    char* ws = (char*)d_ws;
    float* rev   = (float*)(ws + OFF_REV);
    float* x1    = (float*)(ws + OFF_X1);
    float* x2    = (float*)(ws + OFF_B);    // encoder output, read by gru_scan
    float* y1    = (float*)(ws + OFF_C);    // fused decoder-1 output
    char*  sb    = ws + OFF_X1;             // slots: 8 reps x 256 KB = 2 MB in dead x1

    build_rev<<<(T_STEPS * 64) / 256, 256, 0, stream>>>(wea, inf, rev);

    // encoder
    gemm_bias_act<<<dim3(8, 128), 256, 0, stream>>>(rev, enc_w1, enc_b1, x1,
                                                    T_STEPS, 512, 64, 1);
    gemm_bias_act<<<dim3(16, 128), 256, 0, stream>>>(x1, enc_w2, enc_b2, x2,
                                                     T_STEPS, 1024, 512, 1);
    // seed all slot replicas (x1 region is now dead) and run the fused scans
    seed_slots<<<32, 256, 0, stream>>>(h_init, sb);
    gru_scan<<<GW, 256, 0, stream>>>(gru_whh, gru_bhh, gru_wih, gru_bih, x2, sb);
    lstm_scan<<<GW, 256, 0, stream>>>(lstm_wih, lstm_bih, lstm_bhh,
                                      dec_w1, dec_b1, sb, y1);

    // final tiny projection
    dec2_kernel<<<T_STEPS / 4, 256, 0, stream>>>(y1, dec_w2, dec_b2, (float*)d_out);
}

// Round 15
// 37918.552 us; speedup vs baseline: 1.1715x; 1.1715x over previous
//
#include <hip/hip_runtime.h>
#include <hip/hip_bf16.h>
#include <math.h>

// Problem constants
#define T_STEPS 8192
#define HDIM    1024
#define GW      128     // workgroups per scan kernel (1 per CU, all co-resident)
#define NSLOT   512     // one slot per wave: 2 h-values + tag
#define SLOT_PITCH 256  // bytes between slots: spread across MALL channels
#define NREP    8       // producer-side replicas; consumer WG g polls replica g&7
#define REP_STRIDE ((size_t)2 * NSLOT * SLOT_PITCH)   // 256 KB per replica

// Workspace layout (bytes)
#define OFF_REV   ((size_t)0)                         // 8192*64*4   = 2 MB
#define OFF_X1    ((size_t)2097152)                   // 8192*512*4  = 16 MB (reused as slots after gemm2)
#define OFF_B     ((size_t)18874368)                  // x2: 8192*1024*4 = 32 MB (read by fused gru scan)
#define OFF_C     ((size_t)52428800)                  // y1: 8192*512*4 = 16 MB (written by fused lstm scan)
#define WS_NEEDED ((size_t)153092096)

typedef float f4 __attribute__((ext_vector_type(4)));

__device__ inline float sigm(float x)   { return 1.0f / (1.0f + __expf(-x)); }
__device__ inline float tanh_f(float x) { float e = __expf(2.0f * x); return 1.0f - 2.0f / (e + 1.0f); }

// slot k of buffer b, replica rep
__device__ inline f4* slot_ptr(char* base, int rep, int b, int k) {
    return (f4*)(base + (size_t)rep * REP_STRIDE + ((size_t)b * NSLOT + k) * SLOT_PITCH);
}

// Device-coherent (L1+L2-bypassing) 16B store: tag travels with data in one
// transaction. MALL is the only working coherence point (R4/R5: remote
// stores never refresh another L2's stale line; sc0-only polling unsound).
__device__ inline void store_cohr(f4* p, f4 v) {
    asm volatile("global_store_dwordx4 %0, %1, off sc0 sc1"
                 :: "v"(p), "v"(v) : "memory");
}

// Paired poll of slots k, k+1 (SLOT_PITCH apart): both loads issued
// back-to-back, ONE wait, both tags checked. s_sleep(1) throttles MALL
// pressure between rounds (R2/R8/R9/R14 lesson: any restructure of this
// loop — faster sampling, pipelining, probe-overlap — regresses).
__device__ inline void poll_pair(const f4* p, unsigned want, f4& a, f4& b) {
    for (;;) {
        f4 va, vb;
        asm volatile("global_load_dwordx4 %0, %2, off sc0 sc1\n\t"
                     "global_load_dwordx4 %1, %2, off offset:256 sc0 sc1\n\t"
                     "s_waitcnt vmcnt(0)"
                     : "=&v"(va), "=&v"(vb) : "v"(p) : "memory");
        if (__float_as_uint(va.w) == want && __float_as_uint(vb.w) == want) {
            a = va; b = vb; return;
        }
        __builtin_amdgcn_s_sleep(1);
    }
}

// ---------------------------------------------------------------------------
// build rev: rev[t][0:32]=weather[T-1-t], rev[t][32:64]=infect[T-1-t]
// ---------------------------------------------------------------------------
__global__ void build_rev(const float* __restrict__ wea, const float* __restrict__ inf,
                          float* __restrict__ rev) {
    int idx = blockIdx.x * blockDim.x + threadIdx.x;   // over T*64
    if (idx >= T_STEPS * 64) return;
    int t = idx >> 6, c = idx & 63;
    int ts = T_STEPS - 1 - t;
    rev[idx] = (c < 32) ? wea[ts * 32 + c] : inf[ts * 32 + (c - 32)];
}

// ---------------------------------------------------------------------------
// seed ALL replicas: buffer 0 with h_init (tag 0), buffer 1 with poison tag
// ---------------------------------------------------------------------------
__global__ void seed_slots(const float* __restrict__ h0, char* __restrict__ sb) {
    int i = blockIdx.x * blockDim.x + threadIdx.x;   // over NREP*2*NSLOT = 8192
    int rep = i >> 10;            // replica index 0..7
    int j   = i & 1023;           // buf*NSLOT + k
    if (rep < NREP) {
        if (j < NSLOT) {
            f4 v;
            v.x = h0[2 * j]; v.y = h0[2 * j + 1]; v.z = 0.0f;
            v.w = __uint_as_float(0u);
            store_cohr(slot_ptr(sb, rep, 0, j), v);
        } else {
            f4 v;
            v.x = 0.f; v.y = 0.f; v.z = 0.f;
            v.w = __uint_as_float(0xFFFFFFFFu);      // poison tag
            store_cohr(slot_ptr(sb, rep, 1, j - NSLOT), v);
        }
    }
}

// ---------------------------------------------------------------------------
// Tiled f32 GEMM: C[M,N] = act(A[M,K] @ W[N,K]^T + bias[N]); BM=BN=64, BK=32
// (encoder layers only; xp and decoder GEMMs are fused into the scans)
// ---------------------------------------------------------------------------
__global__ __launch_bounds__(256) void gemm_bias_act(
    const float* __restrict__ A, const float* __restrict__ W,
    const float* __restrict__ bias, float* __restrict__ C,
    int M, int N, int K, int relu)
{
    __shared__ float As[32][68];
    __shared__ float Ws[32][68];
    const int tid = threadIdx.x;
    const int tx = tid & 15, ty = tid >> 4;
    const int bm = blockIdx.y, bn = blockIdx.x;
    const float* Ab = A + (size_t)bm * 64 * K;
    const float* Wb = W + (size_t)bn * 64 * K;
    float acc[4][4] = {};

    for (int k0 = 0; k0 < K; k0 += 32) {
#pragma unroll
        for (int q = 0; q < 2; ++q) {
            int idx = tid * 2 + q;           // 0..511
            int row = idx >> 3;              // 0..63
            int kc  = (idx & 7) << 2;        // 0..28
            float4 av = *(const float4*)(Ab + (size_t)row * K + k0 + kc);
            As[kc + 0][row] = av.x; As[kc + 1][row] = av.y;
            As[kc + 2][row] = av.z; As[kc + 3][row] = av.w;
            float4 wv = *(const float4*)(Wb + (size_t)row * K + k0 + kc);
            Ws[kc + 0][row] = wv.x; Ws[kc + 1][row] = wv.y;
            Ws[kc + 2][row] = wv.z; Ws[kc + 3][row] = wv.w;
        }
        __syncthreads();
#pragma unroll
        for (int k = 0; k < 32; ++k) {
            float4 a = *(const float4*)&As[k][ty << 2];
            float4 b = *(const float4*)&Ws[k][tx << 2];
            acc[0][0] += a.x*b.x; acc[0][1] += a.x*b.y; acc[0][2] += a.x*b.z; acc[0][3] += a.x*b.w;
            acc[1][0] += a.y*b.x; acc[1][1] += a.y*b.y; acc[1][2] += a.y*b.z; acc[1][3] += a.y*b.w;
            acc[2][0] += a.z*b.x; acc[2][1] += a.z*b.y; acc[2][2] += a.z*b.z; acc[2][3] += a.z*b.w;
            acc[3][0] += a.w*b.x; acc[3][1] += a.w*b.y; acc[3][2] += a.w*b.z; acc[3][3] += a.w*b.w;
        }
        __syncthreads();
    }

    int m0 = bm * 64 + (ty << 2), n0 = bn * 64 + (tx << 2);
    float4 bv = *(const float4*)(bias + n0);
#pragma unroll
    for (int r = 0; r < 4; ++r) {
        float4 o;
        o.x = acc[r][0] + bv.x; o.y = acc[r][1] + bv.y;
        o.z = acc[r][2] + bv.z; o.w = acc[r][3] + bv.w;
        if (relu) {
            o.x = fmaxf(o.x, 0.f); o.y = fmaxf(o.y, 0.f);
            o.z = fmaxf(o.z, 0.f); o.w = fmaxf(o.w, 0.f);
        }
        *(float4*)(C + (size_t)(m0 + r) * N + n0) = o;
    }
}

// ---------------------------------------------------------------------------
// GRU scan with FUSED input projection. 128 WGs x 256 thr; wave wv=g*4+w
// owns h[2wv],h[2wv+1]. whh rows AND wih rows pinned in VGPRs. The xp values
// for step t+1 (x2[t+1]·wih_rows + bih) are computed AFTER publish — the
// ~0.3µs sits on the step path but replaces the 3.4ms xp GEMM (net win,
// R13 verified; probe-overlap variants regress, R14).
// Tags: read tag t from buffer t&1, publish tag t+1 into buffer (t+1)&1.
// REPLICATED publish (R10, +7%): lanes 0..7 store 8 replicas in one wave op.
// ---------------------------------------------------------------------------
__global__ __launch_bounds__(256, 1) void gru_scan(
    const float* __restrict__ whh,   // 3072x1024
    const float* __restrict__ bhh,   // 3072
    const float* __restrict__ wih,   // 3072x1024
    const float* __restrict__ bih,   // 3072
    const float* __restrict__ x2,    // 8192x1024 (encoder output)
    char* __restrict__ sb)           // slot base: NREP x 2 x NSLOT x 256B
{
    __shared__ float h_sh[2][HDIM];
    const int g = blockIdx.x, tid = threadIdx.x;
    const int w = tid >> 6, l = tid & 63;
    const int wv = g * 4 + w;
    const int rep = g & (NREP - 1);
    const int iA = 2 * wv, iB = iA + 1;
    const int rows[6] = { iA, HDIM + iA, 2*HDIM + iA, iB, HDIM + iB, 2*HDIM + iB };

    // weights -> VGPRs: lane l holds w[row][256j + 4l .. +3]
    f4 Wf[6][4], Wi[6][4];
#pragma unroll
    for (int r = 0; r < 6; ++r) {
        const float* wr = whh + (size_t)rows[r] * HDIM + 4 * l;
        const float* wr2 = wih + (size_t)rows[r] * HDIM + 4 * l;
#pragma unroll
        for (int j = 0; j < 4; ++j) {
            Wf[r][j] = *(const f4*)(wr + 256 * j);
            Wi[r][j] = *(const f4*)(wr2 + 256 * j);
        }
    }
#pragma unroll
    for (int r = 0; r < 6; ++r)
#pragma unroll
        for (int j = 0; j < 4; ++j) {
            asm volatile("" : "+v"(Wf[r][j]));   // pin: opaque def, cannot remat
            asm volatile("" : "+v"(Wi[r][j]));
        }

    // per-output constants on lanes 0 (output iA) and 1 (output iB)
    float b0 = 0.f, b1 = 0.f, b2 = 0.f;
    float bi0 = 0.f, bi1 = 0.f, bi2 = 0.f;
    float xv0 = 0.f, xv1 = 0.f, xv2 = 0.f;
    int xrow = (l == 0) ? iA : iB;
    if (l < 2) {
        b0  = bhh[xrow]; b1  = bhh[HDIM + xrow]; b2  = bhh[2*HDIM + xrow];
        bi0 = bih[xrow]; bi1 = bih[HDIM + xrow]; bi2 = bih[2*HDIM + xrow];
    }

    // prologue: xp values for t=0
    {
        const float* xr = x2 + 4 * l;
        f4 x4p[4];
#pragma unroll
        for (int j = 0; j < 4; ++j) x4p[j] = *(const f4*)(xr + 256 * j);
        float xred[6];
#pragma unroll
        for (int r = 0; r < 6; ++r) {
            f4 p = Wi[r][0]*x4p[0] + Wi[r][1]*x4p[1] + Wi[r][2]*x4p[2] + Wi[r][3]*x4p[3];
            float v = p.x + p.y + p.z + p.w;
#pragma unroll
            for (int off = 32; off > 0; off >>= 1) v += __shfl_xor(v, off, 64);
            xred[r] = v;
        }
        if (l < 2) {
            xv0 = ((l == 0) ? xred[0] : xred[3]) + bi0;
            xv1 = ((l == 0) ? xred[1] : xred[4]) + bi1;
            xv2 = ((l == 0) ? xred[2] : xred[5]) + bi2;
        }
    }

    for (int t = 0; t < T_STEPS; ++t) {
        const int buf = t & 1;
        // poll the two slots this thread stages, from this WG's replica
        f4 sa, sb2;
        poll_pair(slot_ptr(sb, rep, buf, 2 * tid), (unsigned)t, sa, sb2);
        h_sh[buf][4*tid + 0] = sa.x;  h_sh[buf][4*tid + 1] = sa.y;
        h_sh[buf][4*tid + 2] = sb2.x; h_sh[buf][4*tid + 3] = sb2.y;
        __syncthreads();

        f4 h4[4];
#pragma unroll
        for (int j = 0; j < 4; ++j) h4[j] = *(const f4*)&h_sh[buf][256*j + 4*l];

        float red[6];
#pragma unroll
        for (int r = 0; r < 6; ++r) {
            f4 p = Wf[r][0]*h4[0] + Wf[r][1]*h4[1] + Wf[r][2]*h4[2] + Wf[r][3]*h4[3];
            float v = p.x + p.y + p.z + p.w;
#pragma unroll
            for (int off = 32; off > 0; off >>= 1) v += __shfl_xor(v, off, 64);
            red[r] = v;
        }

        // gate math: lane0 -> output iA, lane1 -> output iB
        float hn = 0.f;
        if (l < 2) {
            float rd0 = (l == 0) ? red[0] : red[3];
            float rd1 = (l == 0) ? red[1] : red[4];
            float rd2 = (l == 0) ? red[2] : red[5];
            float hh_r = rd0 + b0, hh_z = rd1 + b1, hh_n = rd2 + b2;
            float r_ = sigm(xv0 + hh_r);
            float z_ = sigm(xv1 + hh_z);
            float n_ = tanh_f(xv2 + r_ * hh_n);
            float hp = h_sh[buf][xrow];
            hn = (1.0f - z_) * n_ + z_ * hp;
        }
        float hAv = __shfl(hn, 0, 64);
        float hBv = __shfl(hn, 1, 64);
        if (l < NREP) {
            unsigned pub = (unsigned)(t + 1);
            f4 s; s.x = hAv; s.y = hBv; s.z = 0.0f; s.w = __uint_as_float(pub);
            store_cohr(slot_ptr(sb, l, (int)(pub & 1), wv), s);
        }
        // fused xp compute for t+1
        if (t + 1 < T_STEPS) {
            const float* xr = x2 + (size_t)(t + 1) * HDIM + 4 * l;
            f4 x4p[4];
#pragma unroll
            for (int j = 0; j < 4; ++j) x4p[j] = *(const f4*)(xr + 256 * j);
            float xred[6];
#pragma unroll
            for (int r = 0; r < 6; ++r) {
                f4 p = Wi[r][0]*x4p[0] + Wi[r][1]*x4p[1] + Wi[r][2]*x4p[2] + Wi[r][3]*x4p[3];
                float v = p.x + p.y + p.z + p.w;
#pragma unroll
                for (int off = 32; off > 0; off >>= 1) v += __shfl_xor(v, off, 64);
                xred[r] = v;
            }
            if (l < 2) {
                xv0 = ((l == 0) ? xred[0] : xred[3]) + bi0;
                xv1 = ((l == 0) ? xred[1] : xred[4]) + bi1;
                xv2 = ((l == 0) ? xred[2] : xred[5]) + bi2;
            }
        }
    }
}

// ---------------------------------------------------------------------------
// LSTM-like decoder scan with FUSED first decoder layer.
// h_new = o*tanh(i*g); forget rows [H,2H) dead. Reads tag 8191+s, publishes
// 8192+s. At step s the FULL h_{s-1} is staged (h4 regs) -> each wave
// computes its one dec_w1 row: y1[s-1][wv] = relu(h4·Wd + b1[wv]), after
// publish. Extra drain iteration s=T covers y1[T-1]. Removes the decoder
// GEMM (~1ms, R13 verified).
// ---------------------------------------------------------------------------
__global__ __launch_bounds__(256, 1) void lstm_scan(
    const float* __restrict__ wih,   // 4096x1024
    const float* __restrict__ bih,   // 4096
    const float* __restrict__ bhh,   // 4096
    const float* __restrict__ w1,    // 512x1024 (dec_w1)
    const float* __restrict__ b1,    // 512      (dec_b1)
    char* __restrict__ sb,           // slot base
    float* __restrict__ y1)          // 8192x512 output
{
    __shared__ float h_sh[2][HDIM];
    const int g = blockIdx.x, tid = threadIdx.x;
    const int w = tid >> 6, l = tid & 63;
    const int wv = g * 4 + w;
    const int rep = g & (NREP - 1);
    const int iA = 2 * wv, iB = iA + 1;
    const int rows[6] = { iA, 2*HDIM + iA, 3*HDIM + iA, iB, 2*HDIM + iB, 3*HDIM + iB };

    f4 Wf[6][4];
#pragma unroll
    for (int r = 0; r < 6; ++r) {
        const float* wr = wih + (size_t)rows[r] * HDIM + 4 * l;
#pragma unroll
        for (int j = 0; j < 4; ++j) Wf[r][j] = *(const f4*)(wr + 256 * j);
    }
    // this wave's dec_w1 row (row wv), lane l holds w1[wv][256j + 4l .. +3]
    f4 Wd[4];
    {
        const float* wr = w1 + (size_t)wv * HDIM + 4 * l;
#pragma unroll
        for (int j = 0; j < 4; ++j) Wd[j] = *(const f4*)(wr + 256 * j);
    }
#pragma unroll
    for (int r = 0; r < 6; ++r)
#pragma unroll
        for (int j = 0; j < 4; ++j)
            asm volatile("" : "+v"(Wf[r][j]));
#pragma unroll
    for (int j = 0; j < 4; ++j)
        asm volatile("" : "+v"(Wd[j]));

    const float db = b1[wv];

    float b0 = 0.f, b1_ = 0.f, b2 = 0.f;
    int xrow = (l == 0) ? iA : iB;
    if (l < 2) {
        b0  = bih[xrow]          + bhh[xrow];
        b1_ = bih[2*HDIM + xrow] + bhh[2*HDIM + xrow];
        b2  = bih[3*HDIM + xrow] + bhh[3*HDIM + xrow];
    }

    for (int s = 1; s <= T_STEPS; ++s) {     // s=T_STEPS: drain-only (y1 last row)
        const unsigned want = (unsigned)(8191 + s);
        const unsigned pub  = (unsigned)(8192 + s);
        const int buf = (int)(want & 1);
        f4 sa, sb2;
        poll_pair(slot_ptr(sb, rep, buf, 2 * tid), want, sa, sb2);
        h_sh[buf][4*tid + 0] = sa.x;  h_sh[buf][4*tid + 1] = sa.y;
        h_sh[buf][4*tid + 2] = sb2.x; h_sh[buf][4*tid + 3] = sb2.y;
        __syncthreads();

        f4 h4[4];
#pragma unroll
        for (int j = 0; j < 4; ++j) h4[j] = *(const f4*)&h_sh[buf][256*j + 4*l];

        if (s < T_STEPS) {
            float red[6];
#pragma unroll
            for (int r = 0; r < 6; ++r) {
                f4 p = Wf[r][0]*h4[0] + Wf[r][1]*h4[1] + Wf[r][2]*h4[2] + Wf[r][3]*h4[3];
                float v = p.x + p.y + p.z + p.w;
#pragma unroll
                for (int off = 32; off > 0; off >>= 1) v += __shfl_xor(v, off, 64);
                red[r] = v;
            }

            float hn = 0.f;
            if (l < 2) {
                float rd0 = (l == 0) ? red[0] : red[3];
                float rd1 = (l == 0) ? red[1] : red[4];
                float rd2 = (l == 0) ? red[2] : red[5];
                float i_ = sigm(rd0 + b0);
                float g_ = tanh_f(rd1 + b1_);
                float o_ = sigm(rd2 + b2);
                hn = o_ * tanh_f(i_ * g_);
            }
            float hAv = __shfl(hn, 0, 64);
            float hBv = __shfl(hn, 1, 64);
            if (l < NREP) {
                f4 sv; sv.x = hAv; sv.y = hBv; sv.z = 0.0f; sv.w = __uint_as_float(pub);
                store_cohr(slot_ptr(sb, l, (int)(pub & 1), wv), sv);
            }
        }

        // fused decoder layer 1: y1[s-1][wv] = relu(h_{s-1}·w1[wv] + b1[wv])
        {
            f4 p = Wd[0]*h4[0] + Wd[1]*h4[1] + Wd[2]*h4[2] + Wd[3]*h4[3];
            float v = p.x + p.y + p.z + p.w;
#pragma unroll
            for (int off = 32; off > 0; off >>= 1) v += __shfl_xor(v, off, 64);
            if (l == 0)
                y1[(size_t)(s - 1) * 512 + wv] = fmaxf(v + db, 0.f);
        }
    }
}

// ---------------------------------------------------------------------------
// Final tiny GEMM: out[t][0:8] = y1[t] @ dec_w2^T + dec_b2, one wave per t
// ---------------------------------------------------------------------------
__global__ __launch_bounds__(256) void dec2_kernel(
    const float* __restrict__ y1,    // 8192x512
    const float* __restrict__ w2,    // 8x512
    const float* __restrict__ b2,    // 8
    float* __restrict__ out)         // 8192x8
{
    const int w = threadIdx.x >> 6, l = threadIdx.x & 63;
    const int t = blockIdx.x * 4 + w;
    const float* yr = y1 + (size_t)t * 512;
    float yv[8];
#pragma unroll
    for (int j = 0; j < 8; ++j) yv[j] = yr[l + 64 * j];
    float o[8];
#pragma unroll
    for (int n = 0; n < 8; ++n) {
        const float* wr = w2 + n * 512;
        float s = 0.f;
#pragma unroll
        for (int j = 0; j < 8; ++j) s += yv[j] * wr[l + 64 * j];
#pragma unroll
        for (int off = 32; off > 0; off >>= 1) s += __shfl_xor(s, off, 64);
        o[n] = s;
    }
    if (l == 0) {
#pragma unroll
        for (int n = 0; n < 8; ++n) out[(size_t)t * 8 + n] = o[n] + b2[n];
    }
}

// ---------------------------------------------------------------------------
extern "C" void kernel_launch(void* const* d_in, const int* in_sizes, int n_in,
                              void* d_out, int out_size, void* d_ws, size_t ws_size,
                              hipStream_t stream)
{
    const float* wea      = (const float*)d_in[0];
    const float* inf      = (const float*)d_in[1];
    const float* h_init   = (const float*)d_in[3];
    const float* enc_w1   = (const float*)d_in[4];
    const float* enc_b1   = (const float*)d_in[5];
    const float* enc_w2   = (const float*)d_in[6];
    const float* enc_b2   = (const float*)d_in[7];
    const float* gru_wih  = (const float*)d_in[8];
    const float* gru_whh  = (const float*)d_in[9];
    const float* gru_bih  = (const float*)d_in[10];
    const float* gru_bhh  = (const float*)d_in[11];
    const float* lstm_wih = (const float*)d_in[12];
    const float* lstm_bih = (const float*)d_in[13];
    const float* lstm_bhh = (const float*)d_in[14];
    const float* dec_w1   = (const float*)d_in[15];
    const float* dec_b1   = (const float*)d_in[16];
    const float* dec_w2   = (const float*)d_in[17];
    const float* dec_b2   = (const float*)d_in[18];

    if (ws_size < WS_NEEDED) return;

    char* ws = (char*)d_ws;
    float* rev   = (float*)(ws + OFF_REV);
    float* x1    = (float*)(ws + OFF_X1);
    float* x2    = (float*)(ws + OFF_B);    // encoder output, read by gru_scan
    float* y1    = (float*)(ws + OFF_C);    // fused decoder-1 output
    char*  sb    = ws + OFF_X1;             // slots: 8 reps x 256 KB = 2 MB in dead x1

    build_rev<<<(T_STEPS * 64) / 256, 256, 0, stream>>>(wea, inf, rev);

    // encoder
    gemm_bias_act<<<dim3(8, 128), 256, 0, stream>>>(rev, enc_w1, enc_b1, x1,
                                                    T_STEPS, 512, 64, 1);
    gemm_bias_act<<<dim3(16, 128), 256, 0, stream>>>(x1, enc_w2, enc_b2, x2,
                                                     T_STEPS, 1024, 512, 1);
    // seed all slot replicas (x1 region is now dead) and run the fused scans
    seed_slots<<<32, 256, 0, stream>>>(h_init, sb);
    gru_scan<<<GW, 256, 0, stream>>>(gru_whh, gru_bhh, gru_wih, gru_bih, x2, sb);
    lstm_scan<<<GW, 256, 0, stream>>>(lstm_wih, lstm_bih, lstm_bhh,
                                      dec_w1, dec_b1, sb, y1);

    // final tiny projection
    dec2_kernel<<<T_STEPS / 4, 256, 0, stream>>>(y1, dec_w2, dec_b2, (float*)d_out);
}